// Round 4
// baseline (1201.302 us; speedup 1.0000x reference)
//
#include <hip/hip_runtime.h>
#include <hip/hip_bf16.h>
#include <stdint.h>

#define DIM   512
#define BATCH 64
#define KENC  1024          // encoded row: [hi(512) | lo(512)]
#define BM    256
#define BN    256
#define BKT   32
#define NKT   16
#define BUFE  32768         // ushorts per LDS buffer (64 KB): 4 planes * 8192

typedef __attribute__((ext_vector_type(8))) short short8;
typedef __attribute__((ext_vector_type(4))) float floatx4;

__device__ __forceinline__ ushort f2bf(float f) {
    __hip_bfloat16 h = __float2bfloat16(f);
    return *(ushort*)&h;
}
__device__ __forceinline__ float bf2f(ushort u) {
    __hip_bfloat16 h = *(__hip_bfloat16*)&u;
    return (float)h;
}

typedef __attribute__((address_space(3))) uint32_t lds_u32;
typedef const __attribute__((address_space(1))) uint32_t glb_u32;
__device__ __forceinline__ void gload16(const ushort* g, ushort* l) {
    __builtin_amdgcn_global_load_lds((glb_u32*)g, (lds_u32*)l, 16, 0, 0);
}

#define WAITVM(N) asm volatile("s_waitcnt vmcnt(" #N ")" ::: "memory")
#define BARRIER() do { __builtin_amdgcn_s_barrier(); __builtin_amdgcn_sched_barrier(0); } while (0)
#define SCHED()   __builtin_amdgcn_sched_barrier(0)

__global__ __launch_bounds__(256) void norm_partial_kernel(const float* __restrict__ x,
                                                           float* __restrict__ partial) {
    int b = blockIdx.y;
    int i = blockIdx.x;
    const float4* xv = (const float4*)(x + (size_t)b * DIM * DIM + (size_t)i * (DIM * DIM / 16));
    float s = 0.f;
    #pragma unroll
    for (int r = 0; r < 16; ++r) {
        float4 v = xv[r * 256 + threadIdx.x];
        s += v.x * v.x + v.y * v.y + v.z * v.z + v.w * v.w;
    }
    #pragma unroll
    for (int off = 32; off > 0; off >>= 1) s += __shfl_down(s, off, 64);
    __shared__ float red[4];
    int lane = threadIdx.x & 63, wid = threadIdx.x >> 6;
    if (lane == 0) red[wid] = s;
    __syncthreads();
    if (threadIdx.x == 0) partial[b * 16 + i] = red[0] + red[1] + red[2] + red[3];
}

__global__ __launch_bounds__(256) void init_kernel(const float* __restrict__ x,
                                                   const float* __restrict__ partial,
                                                   float* __restrict__ norms,
                                                   ushort* __restrict__ Yenc,
                                                   ushort* __restrict__ Tenc) {
    int b = blockIdx.y;
    float s = 0.f;
    #pragma unroll
    for (int p = 0; p < 16; ++p) s += partial[b * 16 + p];
    float nrm = sqrtf(s);
    if (blockIdx.x == 0 && threadIdx.x == 0) norms[b] = nrm;
    float inv = 1.0f / nrm;
    int idx = (blockIdx.x * 256 + threadIdx.x) * 4;
    int r = idx >> 9;
    int c = idx & 511;
    float4 v = *(const float4*)(x + (size_t)b * DIM * DIM + idx);
    float yv[4] = {v.x * inv, v.y * inv, v.z * inv, v.w * inv};
    size_t base = (size_t)b * DIM * KENC + (size_t)r * KENC;
    ushort yhi[4], ylo[4], thi[4], tlo[4];
    #pragma unroll
    for (int j = 0; j < 4; ++j) {
        float y = yv[j];
        yhi[j] = f2bf(y);
        ylo[j] = f2bf(y - bf2f(yhi[j]));
        float t = ((c + j) == r ? 1.5f : 0.0f) - 0.5f * y;
        thi[j] = f2bf(t);
        tlo[j] = f2bf(t - bf2f(thi[j]));
    }
    *(ushort4*)(Yenc + base + c)       = *(ushort4*)yhi;
    *(ushort4*)(Yenc + base + 512 + c) = *(ushort4*)ylo;
    *(ushort4*)(Tenc + base + c)       = *(ushort4*)thi;
    *(ushort4*)(Tenc + base + 512 + c) = *(ushort4*)tlo;
}

// Stage one K-tile's HI unit (Ahi plane @0, Bhi plane @16384): 4 gloads/thread.
// plane layout: 256 rows * 32 elem; physical chunk pc of row r holds logical
// chunk pc ^ ((r>>1)&3). LDS dest = base + vt*16B (lane-ordered, DMA-legal).
__device__ __forceinline__ void stage_hi(ushort* buf, const ushort* Ag, const ushort* Bg,
                                         int k0, int tid) {
    #pragma unroll
    for (int s = 0; s < 2; ++s) {
        int vt = tid + s * 512;
        int row = vt >> 2;
        int pc  = vt & 3;
        int kc  = ((pc ^ ((row >> 1) & 3)) << 3);
        const ushort* ar = Ag + (size_t)row * KENC + k0 + kc;
        const ushort* br = Bg + (size_t)row * KENC + k0 + kc;
        gload16(ar, &buf[vt * 8]);              // Ahi
        gload16(br, &buf[16384 + vt * 8]);      // Bhi
    }
}
// LO unit (Alo @8192, Blo @24576): 4 gloads/thread, issued one barrier-region later.
__device__ __forceinline__ void stage_lo(ushort* buf, const ushort* Ag, const ushort* Bg,
                                         int k0, int tid) {
    #pragma unroll
    for (int s = 0; s < 2; ++s) {
        int vt = tid + s * 512;
        int row = vt >> 2;
        int pc  = vt & 3;
        int kc  = ((pc ^ ((row >> 1) & 3)) << 3);
        const ushort* ar = Ag + (size_t)row * KENC + k0 + kc;
        const ushort* br = Bg + (size_t)row * KENC + k0 + kc;
        gload16(ar + 512, &buf[8192 + vt * 8]);   // Alo
        gload16(br + 512, &buf[24576 + vt * 8]);  // Blo
    }
}

__device__ __forceinline__ void store_enc(ushort* Cenc, size_t matoff, int gr, int gc, float v) {
    ushort hi = f2bf(v);
    ushort lo = f2bf(v - bf2f(hi));
    Cenc[matoff + (size_t)gr * KENC + gc] = hi;
    Cenc[matoff + (size_t)gr * KENC + 512 + gc] = lo;
}

// 256x256 tile, 512 threads (8 waves, each a 128x64 sub-tile), double-buffered LDS.
// Software-pipelined 6-phase schedule (m201-style, 1-phase register lookahead):
// every phase issues the ds_reads feeding the NEXT phase's MFMA cluster, then runs
// the current cluster on registers loaded a phase earlier -- so each LDS burst
// hides under the previous MFMA cluster instead of stalling its own. 2 runtime
// barriers/tile (counted vmcnt: lo-unit published at P2, next-hi at P5); never a
// mid-loop vmcnt(0). setprio(1) around each MFMA cluster.
// Hazards: lo-dependent reads only after P2 barrier; nxt-hi reads only after P5
// barrier; read->overwrite safe since each read is lgkm-drained by its consuming
// MFMA >=1 barrier before the overwriting stage lands (audited for hi+lo regions).
// MODE 0: T-enc = 1.5I - 0.5*C   MODE 1: C-enc   MODE 2: fp32 C*sqrt(normA)
template <int MODE>
__global__ __launch_bounds__(512, 2) void gemm_bt(const ushort* __restrict__ A,
                                                  const ushort* __restrict__ B,
                                                  ushort* __restrict__ Cenc,
                                                  float* __restrict__ Cout,
                                                  const float* __restrict__ norms) {
    __shared__ __attribute__((aligned(16))) ushort sm[2 * BUFE];  // 128 KB

    int f = blockIdx.x;           // 256 blocks: 64 matrices x 4 quadrant-tiles
    int xcd = f & 7;
    int g   = f >> 3;             // 0..31
    int b   = xcd + 8 * (g >> 2); // 8 matrices per XCD (4 co-tiles each)
    int t   = g & 3;
    int bm  = t >> 1;
    int bn  = t & 1;

    size_t matoff = (size_t)b * DIM * KENC;
    const ushort* Ag = A + matoff + (size_t)bm * BM * KENC;
    const ushort* Bg = B + matoff + (size_t)bn * BN * KENC;

    int tid = threadIdx.x;
    int wave = tid >> 6, lane = tid & 63;
    int lane15 = lane & 15, quad = lane >> 4;
    int wrow = (wave >> 2) * 128;   // 2 row-groups of 128
    int wcol = (wave & 3) * 64;     // 4 col-groups of 64
    int s2 = (lane15 >> 1) & 3;
    int fo = ((quad ^ s2) << 3);

    floatx4 acc[8][4];
    #pragma unroll
    for (int i = 0; i < 8; ++i)
        #pragma unroll
        for (int j = 0; j < 4; ++j)
            acc[i][j] = (floatx4){0.f, 0.f, 0.f, 0.f};

    // prologue: stage tile 0 (hi then lo, 8 loads out); publish hi; preload M1 regs
    stage_hi(sm, Ag, Bg, 0, tid);
    stage_lo(sm, Ag, Bg, 0, tid);
    WAITVM(4);          // hi(0) landed; lo(0) still in flight
    BARRIER();

    short8 a03[4], b_h[4];
    #pragma unroll
    for (int i = 0; i < 4; ++i)
        a03[i] = *(const short8*)&sm[(wrow + i * 16 + lane15) * BKT + fo];
    #pragma unroll
    for (int j = 0; j < 4; ++j)
        b_h[j] = *(const short8*)&sm[16384 + (wcol + j * 16 + lane15) * BKT + fo];

    #pragma unroll 2
    for (int kt = 0; kt < NKT; ++kt) {
        const ushort* cur = sm + (kt & 1) * BUFE;
        ushort* nxt = sm + ((kt + 1) & 1) * BUFE;
        const ushort* Ash = cur;
        const ushort* Asl = cur + 8192;
        const ushort* Bsh = cur + 16384;
        const ushort* Bsl = cur + 24576;

        short8 a47[4], b_l[4], l03[4], l47[4], na[4], nb[4];

        // -- P1: reads ah[4..7] (for M2); stage next hi; MFMA M1 = ah03 x bh --
        #pragma unroll
        for (int i = 0; i < 4; ++i)
            a47[i] = *(const short8*)&Ash[(wrow + (i + 4) * 16 + lane15) * BKT + fo];
        if (kt + 1 < NKT) stage_hi(nxt, Ag, Bg, (kt + 1) * BKT, tid);
        SCHED();
        __builtin_amdgcn_s_setprio(1);
        #pragma unroll
        for (int i = 0; i < 4; ++i)
            #pragma unroll
            for (int j = 0; j < 4; ++j)
                acc[i][j] = __builtin_amdgcn_mfma_f32_16x16x32_bf16(a03[i], b_h[j], acc[i][j], 0, 0, 0);
        __builtin_amdgcn_s_setprio(0);
        SCHED();

        // -- P2: publish lo(kt); reads bl (for M3); MFMA M2 = ah47 x bh --
        if (kt + 1 < NKT) { WAITVM(4); }   // outstanding: lo(kt)+hi(kt+1)=8 -> lo landed
        else             { WAITVM(0); }    // tail: only lo(kt) outstanding
        BARRIER();
        #pragma unroll
        for (int j = 0; j < 4; ++j)
            b_l[j] = *(const short8*)&Bsl[(wcol + j * 16 + lane15) * BKT + fo];
        SCHED();
        __builtin_amdgcn_s_setprio(1);
        #pragma unroll
        for (int i = 0; i < 4; ++i)
            #pragma unroll
            for (int j = 0; j < 4; ++j)
                acc[i + 4][j] = __builtin_amdgcn_mfma_f32_16x16x32_bf16(a47[i], b_h[j], acc[i + 4][j], 0, 0, 0);
        __builtin_amdgcn_s_setprio(0);
        SCHED();

        // -- P3: reads al[0..3] (for M5); stage next lo; MFMA M3 = ah03 x bl --
        #pragma unroll
        for (int i = 0; i < 4; ++i)
            l03[i] = *(const short8*)&Asl[(wrow + i * 16 + lane15) * BKT + fo];
        if (kt + 1 < NKT) stage_lo(nxt, Ag, Bg, (kt + 1) * BKT, tid);
        SCHED();
        __builtin_amdgcn_s_setprio(1);
        #pragma unroll
        for (int i = 0; i < 4; ++i)
            #pragma unroll
            for (int j = 0; j < 4; ++j)
                acc[i][j] = __builtin_amdgcn_mfma_f32_16x16x32_bf16(a03[i], b_l[j], acc[i][j], 0, 0, 0);
        __builtin_amdgcn_s_setprio(0);
        SCHED();

        // -- P4: reads al[4..7] (for M6); MFMA M4 = ah47 x bl --
        #pragma unroll
        for (int i = 0; i < 4; ++i)
            l47[i] = *(const short8*)&Asl[(wrow + (i + 4) * 16 + lane15) * BKT + fo];
        SCHED();
        __builtin_amdgcn_s_setprio(1);
        #pragma unroll
        for (int i = 0; i < 4; ++i)
            #pragma unroll
            for (int j = 0; j < 4; ++j)
                acc[i + 4][j] = __builtin_amdgcn_mfma_f32_16x16x32_bf16(a47[i], b_l[j], acc[i + 4][j], 0, 0, 0);
        __builtin_amdgcn_s_setprio(0);
        SCHED();

        // -- P5: publish hi(kt+1); reads bh' (for next M1); MFMA M5 = al03 x bh --
        if (kt + 1 < NKT) {
            WAITVM(4);                     // outstanding: hi(kt+1)+lo(kt+1)=8 -> hi landed
            BARRIER();
            #pragma unroll
            for (int j = 0; j < 4; ++j)
                nb[j] = *(const short8*)&nxt[16384 + (wcol + j * 16 + lane15) * BKT + fo];
        }
        SCHED();
        __builtin_amdgcn_s_setprio(1);
        #pragma unroll
        for (int i = 0; i < 4; ++i)
            #pragma unroll
            for (int j = 0; j < 4; ++j)
                acc[i][j] = __builtin_amdgcn_mfma_f32_16x16x32_bf16(l03[i], b_h[j], acc[i][j], 0, 0, 0);
        __builtin_amdgcn_s_setprio(0);
        SCHED();

        // -- P6: reads ah03' (for next M1); MFMA M6 = al47 x bh --
        if (kt + 1 < NKT) {
            #pragma unroll
            for (int i = 0; i < 4; ++i)
                na[i] = *(const short8*)&nxt[(wrow + i * 16 + lane15) * BKT + fo];
        }
        SCHED();
        __builtin_amdgcn_s_setprio(1);
        #pragma unroll
        for (int i = 0; i < 4; ++i)
            #pragma unroll
            for (int j = 0; j < 4; ++j)
                acc[i + 4][j] = __builtin_amdgcn_mfma_f32_16x16x32_bf16(l47[i], b_h[j], acc[i + 4][j], 0, 0, 0);
        __builtin_amdgcn_s_setprio(0);
        SCHED();

        // carry next-tile M1 operands (unroll-2 renames these, no real moves)
        if (kt + 1 < NKT) {
            #pragma unroll
            for (int i = 0; i < 4; ++i) { a03[i] = na[i]; b_h[i] = nb[i]; }
        }
    }

    float scale = (MODE == 2) ? sqrtf(norms[b]) : 0.f;
    #pragma unroll
    for (int i = 0; i < 8; ++i) {
        int gr0 = bm * BM + wrow + i * 16 + quad * 4;
        #pragma unroll
        for (int j = 0; j < 4; ++j) {
            int gc = bn * BN + wcol + j * 16 + lane15;
            #pragma unroll
            for (int rr = 0; rr < 4; ++rr) {
                int gr = gr0 + rr;
                float cv = acc[i][j][rr];
                if (MODE == 0) {
                    store_enc(Cenc, matoff, gr, gc, (gr == gc ? 1.5f : 0.0f) - 0.5f * cv);
                } else if (MODE == 1) {
                    store_enc(Cenc, matoff, gr, gc, cv);
                } else {
                    Cout[(size_t)b * DIM * DIM + (size_t)gr * DIM + gc] = cv * scale;
                }
            }
        }
    }
}

extern "C" void kernel_launch(void* const* d_in, const int* in_sizes, int n_in,
                              void* d_out, int out_size, void* d_ws, size_t ws_size,
                              hipStream_t stream) {
    const float* x = (const float*)d_in[0];  // d_in[1] = I, unused
    float* out = (float*)d_out;

    const size_t MATB = (size_t)BATCH * DIM * KENC * sizeof(ushort);  // 64 MB
    char* ws = (char*)d_ws;
    ushort* W0 = (ushort*)(ws + 0 * MATB);
    ushort* W1 = (ushort*)(ws + 1 * MATB);
    ushort* W2 = (ushort*)(ws + 2 * MATB);
    float* partial = (float*)(ws + 3 * MATB);          // 192 MB + 4 KB total
    float* norms   = (float*)(ws + 3 * MATB + 4096);
    ushort* D = (ushort*)d_out;  // encoded scratch slot #4; final fp32 GEMM overwrites last

    dim3 gblk(512);
    dim3 g1(256);

    norm_partial_kernel<<<dim3(16, BATCH), 256, 0, stream>>>(x, partial);
    init_kernel<<<dim3(256, BATCH), 256, 0, stream>>>(x, partial, norms, W0, W1);  // Y0->W0, T1(=Z1)->W1

    // iter 1: Y1 = Y0*T1 -> W2 ; Z1 = T1 (W1).             live: Y1=W2, Z1=W1   free: W0, D
    gemm_bt<1><<<g1, gblk, 0, stream>>>(W0, W1, W2, nullptr, nullptr);
    // iter 2: T2 = f(Z1*Y1) -> W0                          live: Y1=W2, Z1=W1, T2=W0   free: D
    gemm_bt<0><<<g1, gblk, 0, stream>>>(W1, W2, W0, nullptr, nullptr);
    gemm_bt<1><<<g1, gblk, 0, stream>>>(W2, W0, D, nullptr, nullptr);   // Y2 -> D
    gemm_bt<1><<<g1, gblk, 0, stream>>>(W0, W1, W2, nullptr, nullptr);  // Z2 = T2*Z1 -> W2
    // iter 3
    gemm_bt<0><<<g1, gblk, 0, stream>>>(W2, D, W0, nullptr, nullptr);   // T3 -> W0
    gemm_bt<1><<<g1, gblk, 0, stream>>>(D, W0, W1, nullptr, nullptr);   // Y3 -> W1
    gemm_bt<1><<<g1, gblk, 0, stream>>>(W0, W2, D, nullptr, nullptr);   // Z3 = T3*Z2 -> D
    // iter 4
    gemm_bt<0><<<g1, gblk, 0, stream>>>(D, W1, W0, nullptr, nullptr);   // T4 -> W0
    gemm_bt<1><<<g1, gblk, 0, stream>>>(W1, W0, W2, nullptr, nullptr);  // Y4 -> W2
    gemm_bt<1><<<g1, gblk, 0, stream>>>(W0, D, W1, nullptr, nullptr);   // Z4 = T4*Z3 -> W1
    // iter 5
    gemm_bt<0><<<g1, gblk, 0, stream>>>(W1, W2, W0, nullptr, nullptr);  // T5 -> W0
    gemm_bt<2><<<g1, gblk, 0, stream>>>(W2, W0, nullptr, out, norms);   // out = Y4*T5*sqrt(n)
}

// Round 5
// 725.765 us; speedup vs baseline: 1.6552x; 1.6552x over previous
//
#include <hip/hip_runtime.h>
#include <hip/hip_bf16.h>
#include <stdint.h>

#define DIM   512
#define BATCH 64
#define KENC  1024          // encoded row: [hi(512) | lo(512)]
#define BM    256
#define BN    256
#define BKT   32
#define NKT   16
#define BUFE  32768         // ushorts per LDS buffer (64 KB): 4 planes * 8192

typedef __attribute__((ext_vector_type(8))) short short8;
typedef __attribute__((ext_vector_type(4))) float floatx4;

__device__ __forceinline__ ushort f2bf(float f) {
    __hip_bfloat16 h = __float2bfloat16(f);
    return *(ushort*)&h;
}
__device__ __forceinline__ float bf2f(ushort u) {
    __hip_bfloat16 h = *(__hip_bfloat16*)&u;
    return (float)h;
}

typedef __attribute__((address_space(3))) uint32_t lds_u32;
typedef const __attribute__((address_space(1))) uint32_t glb_u32;
__device__ __forceinline__ void gload16(const ushort* g, ushort* l) {
    __builtin_amdgcn_global_load_lds((glb_u32*)g, (lds_u32*)l, 16, 0, 0);
}

#define WAITVM(N) asm volatile("s_waitcnt vmcnt(" #N ")" ::: "memory")
#define BARRIER() do { __builtin_amdgcn_s_barrier(); __builtin_amdgcn_sched_barrier(0); } while (0)

__global__ __launch_bounds__(256) void norm_partial_kernel(const float* __restrict__ x,
                                                           float* __restrict__ partial) {
    int b = blockIdx.y;
    int i = blockIdx.x;
    const float4* xv = (const float4*)(x + (size_t)b * DIM * DIM + (size_t)i * (DIM * DIM / 16));
    float s = 0.f;
    #pragma unroll
    for (int r = 0; r < 16; ++r) {
        float4 v = xv[r * 256 + threadIdx.x];
        s += v.x * v.x + v.y * v.y + v.z * v.z + v.w * v.w;
    }
    #pragma unroll
    for (int off = 32; off > 0; off >>= 1) s += __shfl_down(s, off, 64);
    __shared__ float red[4];
    int lane = threadIdx.x & 63, wid = threadIdx.x >> 6;
    if (lane == 0) red[wid] = s;
    __syncthreads();
    if (threadIdx.x == 0) partial[b * 16 + i] = red[0] + red[1] + red[2] + red[3];
}

__global__ __launch_bounds__(256) void init_kernel(const float* __restrict__ x,
                                                   const float* __restrict__ partial,
                                                   float* __restrict__ norms,
                                                   ushort* __restrict__ Yenc,
                                                   ushort* __restrict__ Tenc) {
    int b = blockIdx.y;
    float s = 0.f;
    #pragma unroll
    for (int p = 0; p < 16; ++p) s += partial[b * 16 + p];
    float nrm = sqrtf(s);
    if (blockIdx.x == 0 && threadIdx.x == 0) norms[b] = nrm;
    float inv = 1.0f / nrm;
    int idx = (blockIdx.x * 256 + threadIdx.x) * 4;
    int r = idx >> 9;
    int c = idx & 511;
    float4 v = *(const float4*)(x + (size_t)b * DIM * DIM + idx);
    float yv[4] = {v.x * inv, v.y * inv, v.z * inv, v.w * inv};
    size_t base = (size_t)b * DIM * KENC + (size_t)r * KENC;
    ushort yhi[4], ylo[4], thi[4], tlo[4];
    #pragma unroll
    for (int j = 0; j < 4; ++j) {
        float y = yv[j];
        yhi[j] = f2bf(y);
        ylo[j] = f2bf(y - bf2f(yhi[j]));
        float t = ((c + j) == r ? 1.5f : 0.0f) - 0.5f * y;
        thi[j] = f2bf(t);
        tlo[j] = f2bf(t - bf2f(thi[j]));
    }
    *(ushort4*)(Yenc + base + c)       = *(ushort4*)yhi;
    *(ushort4*)(Yenc + base + 512 + c) = *(ushort4*)ylo;
    *(ushort4*)(Tenc + base + c)       = *(ushort4*)thi;
    *(ushort4*)(Tenc + base + 512 + c) = *(ushort4*)tlo;
}

// Stage one K-tile's HI unit (Ahi plane @0, Bhi plane @16384): 4 gloads/thread.
// plane layout: 256 rows * 32 elem; physical chunk pc of row r holds logical
// chunk pc ^ ((r>>1)&3). LDS dest = base + vt*16B (lane-ordered, DMA-legal).
__device__ __forceinline__ void stage_hi(ushort* buf, const ushort* Ag, const ushort* Bg,
                                         int k0, int tid) {
    #pragma unroll
    for (int s = 0; s < 2; ++s) {
        int vt = tid + s * 512;
        int row = vt >> 2;
        int pc  = vt & 3;
        int kc  = ((pc ^ ((row >> 1) & 3)) << 3);
        const ushort* ar = Ag + (size_t)row * KENC + k0 + kc;
        const ushort* br = Bg + (size_t)row * KENC + k0 + kc;
        gload16(ar, &buf[vt * 8]);              // Ahi
        gload16(br, &buf[16384 + vt * 8]);      // Bhi
    }
}
// LO unit (Alo @8192, Blo @24576): 4 gloads/thread, issued one region later.
__device__ __forceinline__ void stage_lo(ushort* buf, const ushort* Ag, const ushort* Bg,
                                         int k0, int tid) {
    #pragma unroll
    for (int s = 0; s < 2; ++s) {
        int vt = tid + s * 512;
        int row = vt >> 2;
        int pc  = vt & 3;
        int kc  = ((pc ^ ((row >> 1) & 3)) << 3);
        const ushort* ar = Ag + (size_t)row * KENC + k0 + kc;
        const ushort* br = Bg + (size_t)row * KENC + k0 + kc;
        gload16(ar + 512, &buf[8192 + vt * 8]);   // Alo
        gload16(br + 512, &buf[24576 + vt * 8]);  // Blo
    }
}

__device__ __forceinline__ void store_enc(ushort* Cenc, size_t matoff, int gr, int gc, float v) {
    ushort hi = f2bf(v);
    ushort lo = f2bf(v - bf2f(hi));
    Cenc[matoff + (size_t)gr * KENC + gc] = hi;
    Cenc[matoff + (size_t)gr * KENC + 512 + gc] = lo;
}

// 256x256 tile, 512 threads (8 waves, each a 128x64 sub-tile), double-buffered LDS.
// 3-region pipelined schedule with ZERO extra operand arrays (register-lean repair
// of the round-4 spill): product order {hh, hl, lh} makes ah/bh/bl/al all dead at
// region-B end, so region C reads NEXT tile's ah/bh into the same registers.
//   A: [stage_hi(kt+1)] [32 MFMA hh on preloaded ah x bh]   <- zero-read region
//      WAITVM(4) publish lo(kt); BARRIER
//   B: [read bl(4), al(8)] [stage_lo(kt+1)] [64 MFMA: ah x bl, al x bh]
//      WAITVM(4) publish hi(kt+1); BARRIER
//   C: [read ah'(8), bh'(4) from nxt]                       <- feeds next A
// Live frags: ah8+bh4+bl4+al8 = 24 (96 VGPR) + acc 128 => ~240 VGPR, no spill.
// vmcnt ledger (4 loads/stage): tile entry invariant = {lo(kt)}=4 outstanding.
//   A issues hi(kt+1) -> 8; WAITVM(4) proves lo(kt). B issues lo(kt+1) -> 8;
//   WAITVM(4) proves hi(kt+1). Never vmcnt(0) mid-loop.
// Overwrite hazards: stage(kt+1) targets buffer[(kt+1)&1] whose last reads were
// drained by their consuming MFMAs >=1 barrier before the stage issues (audited).
// MODE 0: T-enc = 1.5I - 0.5*C   MODE 1: C-enc   MODE 2: fp32 C*sqrt(normA)
template <int MODE>
__global__ __launch_bounds__(512, 2) void gemm_bt(const ushort* __restrict__ A,
                                                  const ushort* __restrict__ B,
                                                  ushort* __restrict__ Cenc,
                                                  float* __restrict__ Cout,
                                                  const float* __restrict__ norms) {
    __shared__ __attribute__((aligned(16))) ushort sm[2 * BUFE];  // 128 KB

    int f = blockIdx.x;           // 256 blocks: 64 matrices x 4 quadrant-tiles
    int xcd = f & 7;
    int g   = f >> 3;             // 0..31
    int b   = xcd + 8 * (g >> 2); // 8 matrices per XCD (4 co-tiles each)
    int t   = g & 3;
    int bm  = t >> 1;
    int bn  = t & 1;

    size_t matoff = (size_t)b * DIM * KENC;
    const ushort* Ag = A + matoff + (size_t)bm * BM * KENC;
    const ushort* Bg = B + matoff + (size_t)bn * BN * KENC;

    int tid = threadIdx.x;
    int wave = tid >> 6, lane = tid & 63;
    int lane15 = lane & 15, quad = lane >> 4;
    int wrow = (wave >> 2) * 128;   // 2 row-groups of 128
    int wcol = (wave & 3) * 64;     // 4 col-groups of 64
    int s2 = (lane15 >> 1) & 3;
    int fo = ((quad ^ s2) << 3);

    floatx4 acc[8][4];
    #pragma unroll
    for (int i = 0; i < 8; ++i)
        #pragma unroll
        for (int j = 0; j < 4; ++j)
            acc[i][j] = (floatx4){0.f, 0.f, 0.f, 0.f};

    // prologue: stage tile 0 (hi, lo); publish hi; preload ah/bh for first A-region
    stage_hi(sm, Ag, Bg, 0, tid);
    stage_lo(sm, Ag, Bg, 0, tid);
    WAITVM(4);          // hi(0) landed; lo(0) still in flight (invariant = 4 out)
    BARRIER();

    short8 ah[8], bh[4], bl[4], al[8];
    #pragma unroll
    for (int i = 0; i < 8; ++i)
        ah[i] = *(const short8*)&sm[(wrow + i * 16 + lane15) * BKT + fo];
    #pragma unroll
    for (int j = 0; j < 4; ++j)
        bh[j] = *(const short8*)&sm[16384 + (wcol + j * 16 + lane15) * BKT + fo];

    for (int kt = 0; kt < NKT; ++kt) {
        const ushort* cur = sm + (kt & 1) * BUFE;
        ushort* nxt = sm + ((kt + 1) & 1) * BUFE;
        const ushort* Asl = cur + 8192;
        const ushort* Bsl = cur + 24576;

        // ---- Region A: stage next hi; 32 MFMA hh (operands already in regs) ----
        if (kt + 1 < NKT) stage_hi(nxt, Ag, Bg, (kt + 1) * BKT, tid);
        __builtin_amdgcn_s_setprio(1);
        #pragma unroll
        for (int i = 0; i < 8; ++i)
            #pragma unroll
            for (int j = 0; j < 4; ++j)
                acc[i][j] = __builtin_amdgcn_mfma_f32_16x16x32_bf16(ah[i], bh[j], acc[i][j], 0, 0, 0);
        __builtin_amdgcn_s_setprio(0);

        // publish lo(kt): outstanding = lo(kt)+hi(kt+1)=8 -> wait to 4 proves lo(kt)
        if (kt + 1 < NKT) { WAITVM(4); } else { WAITVM(0); }
        BARRIER();

        // ---- Region B: read bl, al; stage next lo; 64 MFMA (hl then lh) ----
        #pragma unroll
        for (int j = 0; j < 4; ++j)
            bl[j] = *(const short8*)&Bsl[(wcol + j * 16 + lane15) * BKT + fo];
        #pragma unroll
        for (int i = 0; i < 8; ++i)
            al[i] = *(const short8*)&Asl[(wrow + i * 16 + lane15) * BKT + fo];
        if (kt + 1 < NKT) stage_lo(nxt, Ag, Bg, (kt + 1) * BKT, tid);
        __builtin_amdgcn_s_setprio(1);
        #pragma unroll
        for (int i = 0; i < 8; ++i)
            #pragma unroll
            for (int j = 0; j < 4; ++j)
                acc[i][j] = __builtin_amdgcn_mfma_f32_16x16x32_bf16(ah[i], bl[j], acc[i][j], 0, 0, 0);
        #pragma unroll
        for (int i = 0; i < 8; ++i)
            #pragma unroll
            for (int j = 0; j < 4; ++j)
                acc[i][j] = __builtin_amdgcn_mfma_f32_16x16x32_bf16(al[i], bh[j], acc[i][j], 0, 0, 0);
        __builtin_amdgcn_s_setprio(0);

        if (kt + 1 < NKT) {
            // publish hi(kt+1): outstanding = hi(kt+1)+lo(kt+1)=8 -> wait to 4
            WAITVM(4);
            BARRIER();
            // ---- Region C: preload next tile's ah/bh (all frags dead here) ----
            #pragma unroll
            for (int i = 0; i < 8; ++i)
                ah[i] = *(const short8*)&nxt[(wrow + i * 16 + lane15) * BKT + fo];
            #pragma unroll
            for (int j = 0; j < 4; ++j)
                bh[j] = *(const short8*)&nxt[16384 + (wcol + j * 16 + lane15) * BKT + fo];
        }
    }

    float scale = (MODE == 2) ? sqrtf(norms[b]) : 0.f;
    #pragma unroll
    for (int i = 0; i < 8; ++i) {
        int gr0 = bm * BM + wrow + i * 16 + quad * 4;
        #pragma unroll
        for (int j = 0; j < 4; ++j) {
            int gc = bn * BN + wcol + j * 16 + lane15;
            #pragma unroll
            for (int rr = 0; rr < 4; ++rr) {
                int gr = gr0 + rr;
                float cv = acc[i][j][rr];
                if (MODE == 0) {
                    store_enc(Cenc, matoff, gr, gc, (gr == gc ? 1.5f : 0.0f) - 0.5f * cv);
                } else if (MODE == 1) {
                    store_enc(Cenc, matoff, gr, gc, cv);
                } else {
                    Cout[(size_t)b * DIM * DIM + (size_t)gr * DIM + gc] = cv * scale;
                }
            }
        }
    }
}

extern "C" void kernel_launch(void* const* d_in, const int* in_sizes, int n_in,
                              void* d_out, int out_size, void* d_ws, size_t ws_size,
                              hipStream_t stream) {
    const float* x = (const float*)d_in[0];  // d_in[1] = I, unused
    float* out = (float*)d_out;

    const size_t MATB = (size_t)BATCH * DIM * KENC * sizeof(ushort);  // 64 MB
    char* ws = (char*)d_ws;
    ushort* W0 = (ushort*)(ws + 0 * MATB);
    ushort* W1 = (ushort*)(ws + 1 * MATB);
    ushort* W2 = (ushort*)(ws + 2 * MATB);
    float* partial = (float*)(ws + 3 * MATB);          // 192 MB + 4 KB total
    float* norms   = (float*)(ws + 3 * MATB + 4096);
    ushort* D = (ushort*)d_out;  // encoded scratch slot #4; final fp32 GEMM overwrites last

    dim3 gblk(512);
    dim3 g1(256);

    norm_partial_kernel<<<dim3(16, BATCH), 256, 0, stream>>>(x, partial);
    init_kernel<<<dim3(256, BATCH), 256, 0, stream>>>(x, partial, norms, W0, W1);  // Y0->W0, T1(=Z1)->W1

    // iter 1: Y1 = Y0*T1 -> W2 ; Z1 = T1 (W1).             live: Y1=W2, Z1=W1   free: W0, D
    gemm_bt<1><<<g1, gblk, 0, stream>>>(W0, W1, W2, nullptr, nullptr);
    // iter 2: T2 = f(Z1*Y1) -> W0                          live: Y1=W2, Z1=W1, T2=W0   free: D
    gemm_bt<0><<<g1, gblk, 0, stream>>>(W1, W2, W0, nullptr, nullptr);
    gemm_bt<1><<<g1, gblk, 0, stream>>>(W2, W0, D, nullptr, nullptr);   // Y2 -> D
    gemm_bt<1><<<g1, gblk, 0, stream>>>(W0, W1, W2, nullptr, nullptr);  // Z2 = T2*Z1 -> W2
    // iter 3
    gemm_bt<0><<<g1, gblk, 0, stream>>>(W2, D, W0, nullptr, nullptr);   // T3 -> W0
    gemm_bt<1><<<g1, gblk, 0, stream>>>(D, W0, W1, nullptr, nullptr);   // Y3 -> W1
    gemm_bt<1><<<g1, gblk, 0, stream>>>(W0, W2, D, nullptr, nullptr);   // Z3 = T3*Z2 -> D
    // iter 4
    gemm_bt<0><<<g1, gblk, 0, stream>>>(D, W1, W0, nullptr, nullptr);   // T4 -> W0
    gemm_bt<1><<<g1, gblk, 0, stream>>>(W1, W0, W2, nullptr, nullptr);  // Y4 -> W2
    gemm_bt<1><<<g1, gblk, 0, stream>>>(W0, D, W1, nullptr, nullptr);   // Z4 = T4*Z3 -> W1
    // iter 5
    gemm_bt<0><<<g1, gblk, 0, stream>>>(W1, W2, W0, nullptr, nullptr);  // T5 -> W0
    gemm_bt<2><<<g1, gblk, 0, stream>>>(W2, W0, nullptr, out, norms);   // out = Y4*T5*sqrt(n)
}